// Round 4
// baseline (419.610 us; speedup 1.0000x reference)
//
#include <hip/hip_runtime.h>

// logsparseAttention == plain CAUSAL attention (no scale) at L=2048, SUB_LEN=5.
// Q,K,V [B,L,H,D] fp32; Out [B,H,L,D] fp32.  B=4, L=2048, H=16, D=64.
// R4: barrier-free streaming flash attention.
//  - prepass (single fused kernel): K -> fp16 [bh][key][d], V -> fp16 [bh][d][key]
//  - main kernel: MFMA fragments loaded DIRECTLY from global (L2-resident),
//    no __syncthreads anywhere; only LDS use is the per-wave P-transpose.
//  - balance: block = 8 waves, waves 0-3 on q-supertile pr, 4-7 on 31-pr
//    -> every block does exactly 132 wave-tiles (fixes R3's CU imbalance).
//  - XCD swizzle: bh grouped by presumed XCD=id%8 for L2 locality.

typedef __attribute__((ext_vector_type(8))) short short8;
typedef __attribute__((ext_vector_type(4))) float floatx4;
typedef _Float16 half8 __attribute__((ext_vector_type(8)));
typedef _Float16 half4 __attribute__((ext_vector_type(4)));

#define NB 4
#define NL 2048
#define NH 16
#define ND 64
#define PADK 72
#define PADQ 72

static __device__ __forceinline__ unsigned short f2bf(float f) {
    unsigned int u = __float_as_uint(f);
    u += 0x7fff + ((u >> 16) & 1);
    return (unsigned short)(u >> 16);
}
static __device__ __forceinline__ float bf2f(unsigned short h) {
    return __uint_as_float(((unsigned int)h) << 16);
}

// ---- fused prepass: K -> Kf [bh][key][d] fp16; V -> Vt [bh][d][key] fp16 ----
__global__ __launch_bounds__(256)
void conv_kv(const float* __restrict__ Kg, const float* __restrict__ Vg,
             _Float16* __restrict__ Kf, _Float16* __restrict__ Vt) {
    __shared__ float tile[64][65];
    const int kt = blockIdx.x;       // key tile 0..31
    const int bh = blockIdx.y;       // 0..63
    const int b  = bh >> 4, h = bh & 15;
    const int t  = threadIdx.x;
    const int row = t >> 2;          // 0..63
    const int seg = (t & 3) * 16;    // 0..48
    const size_t gsrc = (((size_t)(b * NL + kt * 64 + row) * NH + h) << 6) + seg;
    {   // K: straight vectorized convert
        float kv[16];
        #pragma unroll
        for (int i = 0; i < 16; i += 4) *(float4*)(kv + i) = *(const float4*)(Kg + gsrc + i);
        half8 o0, o1;
        #pragma unroll
        for (int j2 = 0; j2 < 8; ++j2) { o0[j2] = (_Float16)kv[j2]; o1[j2] = (_Float16)kv[8 + j2]; }
        _Float16* kd = Kf + (((size_t)(bh * NL + kt * 64 + row)) << 6) + seg;
        *(half8*)kd = o0;
        *(half8*)(kd + 8) = o1;
    }
    {   // V phase 1: fp32 tile into LDS
        #pragma unroll
        for (int i = 0; i < 16; i += 4) {
            float4 v = *(const float4*)(Vg + gsrc + i);
            tile[row][seg + i + 0] = v.x;
            tile[row][seg + i + 1] = v.y;
            tile[row][seg + i + 2] = v.z;
            tile[row][seg + i + 3] = v.w;
        }
    }
    __syncthreads();
    #pragma unroll
    for (int pass = 0; pass < 2; ++pass) {   // V phase 2: transpose out as fp16
        const int d  = pass * 32 + (t >> 3);
        const int kk = (t & 7) * 8;
        half8 o;
        #pragma unroll
        for (int j2 = 0; j2 < 8; ++j2) o[j2] = (_Float16)tile[kk + j2][d];
        *(half8*)(Vt + (((size_t)(bh * 64 + d)) << 11) + kt * 64 + kk) = o;
    }
}

// ------------------------------- main kernel --------------------------------
__global__ __launch_bounds__(512, 4)
void lsattn_main(const float* __restrict__ Qg,
                 const _Float16* __restrict__ Kf,
                 const _Float16* __restrict__ Vt,
                 float* __restrict__ Og) {
    __shared__ alignas(16) _Float16 Ps[8 * 16 * PADQ];   // per-wave P buffer

    const int id  = (int)blockIdx.y * 16 + (int)blockIdx.x;  // dispatch-linear
    const int bh  = (id & 7) * 8 + ((id >> 3) & 7);          // XCD-local bh group
    const int pr  = id >> 6;                                 // q-pair index 0..15
    const int tid  = threadIdx.x;
    const int lane = tid & 63;
    const int w    = tid >> 6;
    const int col  = lane & 15;
    const int quad = lane >> 4;

    const int sa    = (w < 4) ? pr : (31 - pr);  // this wave's 64-q supertile
    const int qbase = sa * 64 + (w & 3) * 16;
    const int qrow  = qbase + col;

    // Q fragment fp32->fp16, B-operand layout
    half8 qf[2];
    {
        const float* qp = Qg + (((size_t)((bh >> 4) * NL + qrow) * NH + (bh & 15)) << 6) + quad * 8;
        #pragma unroll
        for (int c = 0; c < 2; ++c) {
            float4 a = *(const float4*)(qp + c * 32);
            float4 b = *(const float4*)(qp + c * 32 + 4);
            qf[c][0] = (_Float16)a.x; qf[c][1] = (_Float16)a.y;
            qf[c][2] = (_Float16)a.z; qf[c][3] = (_Float16)a.w;
            qf[c][4] = (_Float16)b.x; qf[c][5] = (_Float16)b.y;
            qf[c][6] = (_Float16)b.z; qf[c][7] = (_Float16)b.w;
        }
    }

    floatx4 ofrag[4];
    #pragma unroll
    for (int i = 0; i < 4; ++i) ofrag[i] = floatx4{0.f, 0.f, 0.f, 0.f};
    float m_run = -1e30f, l_run = 0.f;

    // global fragment base pointers (int offsets stay < 2^31)
    const _Float16* kb = Kf + (((size_t)(bh * NL + col)) << 6) + quad * 8;  // + (j0+f*16)*64 + c*32
    const _Float16* vb = Vt + (((size_t)(bh * 64 + col)) << 11) + quad * 8; // + (mc*16)<<11 + j0 + kc*32
    _Float16* pbuf = Ps + w * 16 * PADQ;

    const int tlast = sa;
    for (int t = 0; t <= tlast; ++t) {
        const int j0 = t * 64;

        // K fragments direct from global (L2-hot)
        half8 kfr[4][2];
        #pragma unroll
        for (int f = 0; f < 4; ++f)
            #pragma unroll
            for (int c = 0; c < 2; ++c)
                kfr[f][c] = *(const half8*)(kb + ((j0 + f * 16) << 6) + c * 32);

        // S^T = K * Q^T
        floatx4 stf[4];
        #pragma unroll
        for (int f = 0; f < 4; ++f) {
            floatx4 acc = floatx4{0.f, 0.f, 0.f, 0.f};
            acc = __builtin_amdgcn_mfma_f32_16x16x32_f16(kfr[f][0], qf[0], acc, 0, 0, 0);
            acc = __builtin_amdgcn_mfma_f32_16x16x32_f16(kfr[f][1], qf[1], acc, 0, 0, 0);
            stf[f] = acc;
        }

        // causal mask only on the wave's final tile
        if (t == tlast) {
            #pragma unroll
            for (int f = 0; f < 4; ++f)
                #pragma unroll
                for (int r = 0; r < 4; ++r) {
                    const int key = j0 + f * 16 + quad * 4 + r;
                    if (key > qrow) stf[f][r] = -1e30f;
                }
        }

        // V^T fragments (independent of softmax; issue early)
        half8 vfr[4][2];
        #pragma unroll
        for (int mc = 0; mc < 4; ++mc)
            #pragma unroll
            for (int kc = 0; kc < 2; ++kc)
                vfr[mc][kc] = *(const half8*)(vb + (((size_t)(mc * 16)) << 11) + j0 + kc * 32);

        // online softmax per query column (lanes {col, col+16, col+32, col+48})
        float mt = -1e30f;
        #pragma unroll
        for (int f = 0; f < 4; ++f)
            #pragma unroll
            for (int r = 0; r < 4; ++r) mt = fmaxf(mt, stf[f][r]);
        mt = fmaxf(mt, __shfl_xor(mt, 16));
        mt = fmaxf(mt, __shfl_xor(mt, 32));
        const float m_new = fmaxf(m_run, mt);
        const float alpha = __expf(m_run - m_new);
        float ls = 0.f;
        #pragma unroll
        for (int f = 0; f < 4; ++f)
            #pragma unroll
            for (int r = 0; r < 4; ++r) {
                const float p = __expf(stf[f][r] - m_new);
                stf[f][r] = p;
                ls += p;
            }
        ls += __shfl_xor(ls, 16);
        ls += __shfl_xor(ls, 32);
        l_run = l_run * alpha + ls;
        m_run = m_new;
        #pragma unroll
        for (int mc = 0; mc < 4; ++mc) ofrag[mc] *= alpha;

        // P^T via per-wave LDS round-trip (wave-private, no barrier)
        #pragma unroll
        for (int f = 0; f < 4; ++f) {
            half4 hp;
            hp[0] = (_Float16)stf[f][0]; hp[1] = (_Float16)stf[f][1];
            hp[2] = (_Float16)stf[f][2]; hp[3] = (_Float16)stf[f][3];
            *(half4*)(pbuf + col * PADQ + f * 16 + quad * 4) = hp;
        }
        half8 pf0 = *(const half8*)(pbuf + col * PADQ + quad * 8);
        half8 pf1 = *(const half8*)(pbuf + col * PADQ + 32 + quad * 8);

        // O^T += V^T * P^T
        #pragma unroll
        for (int mc = 0; mc < 4; ++mc) {
            ofrag[mc] = __builtin_amdgcn_mfma_f32_16x16x32_f16(vfr[mc][0], pf0, ofrag[mc], 0, 0, 0);
            ofrag[mc] = __builtin_amdgcn_mfma_f32_16x16x32_f16(vfr[mc][1], pf1, ofrag[mc], 0, 0, 0);
        }
    }

    // epilogue
    const float inv = 1.f / l_run;
    float* op = Og + ((size_t)bh * NL + qrow) * ND;
    #pragma unroll
    for (int mc = 0; mc < 4; ++mc) {
        float4 o;
        o.x = ofrag[mc][0] * inv;
        o.y = ofrag[mc][1] * inv;
        o.z = ofrag[mc][2] * inv;
        o.w = ofrag[mc][3] * inv;
        *(float4*)(op + mc * 16 + quad * 4) = o;
    }
}

// ===================== fallback (round-2 kernel, passed) =====================
__global__ __launch_bounds__(256)
void lsattn_fb(const float* __restrict__ Qg,
               const float* __restrict__ Kg,
               const float* __restrict__ Vg,
               float* __restrict__ Og) {
    __shared__ alignas(16) unsigned short Kh[64 * PADK];
    __shared__ alignas(16) unsigned short Kl[64 * PADK];
    __shared__ alignas(16) unsigned short Vh[64 * PADK];

    const int qt   = 31 - (int)blockIdx.x;
    const int bh   = blockIdx.y;
    const int tid  = threadIdx.x;
    const int lane = tid & 63;
    const int w    = tid >> 6;
    const int col  = lane & 15;
    const int quad = lane >> 4;
    const int qrow = qt * 64 + w * 16 + col;

    short8 qhi[2], qlo[2];
    {
        const float* qp = Qg + ((bh >> 4) * NL + qrow) * (NH * ND) + (bh & 15) * ND + quad * 8;
        #pragma unroll
        for (int c = 0; c < 2; ++c) {
            float qv[8];
            *(float4*)(qv + 0) = *(const float4*)(qp + c * 32);
            *(float4*)(qv + 4) = *(const float4*)(qp + c * 32 + 4);
            #pragma unroll
            for (int j = 0; j < 8; ++j) {
                unsigned short h = f2bf(qv[j]);
                qhi[c][j] = (short)h;
                qlo[c][j] = (short)f2bf(qv[j] - bf2f(h));
            }
        }
    }
    floatx4 ofrag[4];
    #pragma unroll
    for (int i = 0; i < 4; ++i) ofrag[i] = floatx4{0.f, 0.f, 0.f, 0.f};
    float m_run = -1e30f, l_run = 0.f;
    const int skey  = tid >> 2;
    const int sdb   = (tid & 3) * 16;
    const int gbase = (bh >> 4) * NL * NH * ND + (bh & 15) * ND;

    for (int t = 0; t <= qt; ++t) {
        const int j0 = t * 64;
        __syncthreads();
        {
            const int gro = gbase + (j0 + skey) * (NH * ND) + sdb;
            float kv[16], vv[16];
            #pragma unroll
            for (int i = 0; i < 16; i += 4) {
                *(float4*)(kv + i) = *(const float4*)(Kg + gro + i);
                *(float4*)(vv + i) = *(const float4*)(Vg + gro + i);
            }
            short8 h0, h1, l0, l1;
            #pragma unroll
            for (int j = 0; j < 8; ++j) {
                unsigned short h = f2bf(kv[j]);
                h0[j] = (short)h; l0[j] = (short)f2bf(kv[j] - bf2f(h));
                unsigned short g = f2bf(kv[8 + j]);
                h1[j] = (short)g; l1[j] = (short)f2bf(kv[8 + j] - bf2f(g));
            }
            *(short8*)(Kh + skey * PADK + sdb)     = h0;
            *(short8*)(Kh + skey * PADK + sdb + 8) = h1;
            *(short8*)(Kl + skey * PADK + sdb)     = l0;
            *(short8*)(Kl + skey * PADK + sdb + 8) = l1;
            #pragma unroll
            for (int i = 0; i < 16; ++i) Vh[(sdb + i) * PADK + skey] = f2bf(vv[i]);
        }
        __syncthreads();

        floatx4 stf[4];
        #pragma unroll
        for (int f = 0; f < 4; ++f) {
            floatx4 acc = floatx4{0.f, 0.f, 0.f, 0.f};
            #pragma unroll
            for (int c = 0; c < 2; ++c) {
                short8 kh = *(const short8*)(Kh + (f * 16 + col) * PADK + c * 32 + quad * 8);
                short8 kl = *(const short8*)(Kl + (f * 16 + col) * PADK + c * 32 + quad * 8);
                acc = __builtin_amdgcn_mfma_f32_16x16x32_bf16(kh, qhi[c], acc, 0, 0, 0);
                acc = __builtin_amdgcn_mfma_f32_16x16x32_bf16(kl, qhi[c], acc, 0, 0, 0);
                acc = __builtin_amdgcn_mfma_f32_16x16x32_bf16(kh, qlo[c], acc, 0, 0, 0);
            }
            stf[f] = acc;
        }
        if (t == qt) {
            #pragma unroll
            for (int f = 0; f < 4; ++f)
                #pragma unroll
                for (int r = 0; r < 4; ++r) {
                    const int key = j0 + f * 16 + quad * 4 + r;
                    if (key > qrow) stf[f][r] = -1e30f;
                }
        }
        float mt = -1e30f;
        #pragma unroll
        for (int f = 0; f < 4; ++f)
            #pragma unroll
            for (int r = 0; r < 4; ++r) mt = fmaxf(mt, stf[f][r]);
        mt = fmaxf(mt, __shfl_xor(mt, 16));
        mt = fmaxf(mt, __shfl_xor(mt, 32));
        const float m_new = fmaxf(m_run, mt);
        const float alpha = __expf(m_run - m_new);
        float ls = 0.f;
        #pragma unroll
        for (int f = 0; f < 4; ++f)
            #pragma unroll
            for (int r = 0; r < 4; ++r) {
                const float p = __expf(stf[f][r] - m_new);
                stf[f][r] = p; ls += p;
            }
        ls += __shfl_xor(ls, 16);
        ls += __shfl_xor(ls, 32);
        l_run = l_run * alpha + ls;
        m_run = m_new;
        #pragma unroll
        for (int mc = 0; mc < 4; ++mc) ofrag[mc] *= alpha;

        short8 pfrag[2];
        #pragma unroll
        for (int kc = 0; kc < 2; ++kc) {
            #pragma unroll
            for (int jj = 0; jj < 8; ++jj) {
                const int r  = jj & 3;
                const int sq = (quad & 1) * 2 + (jj >> 2);
                const int sl = col + (sq << 4);
                const float va = __shfl(stf[kc * 2 + 0][r], sl);
                const float vb = __shfl(stf[kc * 2 + 1][r], sl);
                pfrag[kc][jj] = (short)f2bf((quad & 2) ? vb : va);
            }
        }
        #pragma unroll
        for (int mc = 0; mc < 4; ++mc) {
            #pragma unroll
            for (int kc = 0; kc < 2; ++kc) {
                short8 vf = *(const short8*)(Vh + (mc * 16 + col) * PADK + kc * 32 + quad * 8);
                ofrag[mc] = __builtin_amdgcn_mfma_f32_16x16x32_bf16(vf, pfrag[kc], ofrag[mc], 0, 0, 0);
            }
        }
    }
    const float inv = 1.f / l_run;
    float* op = Og + ((size_t)bh * NL + qrow) * ND;
    #pragma unroll
    for (int mc = 0; mc < 4; ++mc) {
        float4 o;
        o.x = ofrag[mc][0] * inv; o.y = ofrag[mc][1] * inv;
        o.z = ofrag[mc][2] * inv; o.w = ofrag[mc][3] * inv;
        *(float4*)(op + mc * 16 + quad * 4) = o;
    }
}

extern "C" void kernel_launch(void* const* d_in, const int* in_sizes, int n_in,
                              void* d_out, int out_size, void* d_ws, size_t ws_size,
                              hipStream_t stream) {
    const float* Q = (const float*)d_in[0];
    const float* K = (const float*)d_in[1];
    const float* V = (const float*)d_in[2];
    float* O = (float*)d_out;

    const size_t elems = (size_t)NB * NL * NH * ND;          // 8,388,608
    if (ws_size >= 2 * elems * sizeof(_Float16)) {           // 32 MiB needed
        _Float16* Kf = (_Float16*)d_ws;
        _Float16* Vt = Kf + elems;
        conv_kv<<<dim3(32, 64), dim3(256), 0, stream>>>(K, V, Kf, Vt);
        lsattn_main<<<dim3(16, 64), dim3(512), 0, stream>>>(Q, Kf, Vt, O);
    } else {
        lsattn_fb<<<dim3(32, 64), dim3(256), 0, stream>>>(Q, K, V, O);
    }
}

// Round 5
// 197.892 us; speedup vs baseline: 2.1204x; 2.1204x over previous
//
#include <hip/hip_runtime.h>

// logsparseAttention == plain CAUSAL attention (no scale) at L=2048, SUB_LEN=5.
// Q,K,V [B,L,H,D] fp32; Out [B,H,L,D] fp32.  B=4, L=2048, H=16, D=64.
// R5: LDS-staged flash attention (R3 core) +
//  - intra-block pairing: waves 0-3 -> supertile pr, waves 4-7 -> 31-pr,
//    both consume one staged tile stream => every block = identical compute
//    (fixes R3's measured CU imbalance, robust to any block->CU mapping)
//  - register prefetch of tile t+1 issued before the 2nd barrier => global
//    latency overlaps barrier + tile-t compute (fixes exposed-latency share)
//  - bh = id&63: XCD (id%8) sees 8 heads -> 4MB K/V working set ~ per-XCD L2.

typedef __attribute__((ext_vector_type(8))) short short8;
typedef __attribute__((ext_vector_type(4))) float floatx4;
typedef _Float16 half8 __attribute__((ext_vector_type(8)));
typedef _Float16 half4 __attribute__((ext_vector_type(4)));

#define NB 4
#define NL 2048
#define NH 16
#define ND 64
#define PADK 72   // 144B row stride, 16B-aligned; staging/read phases conflict-free
#define PADQ 72   // Ps rows hold 64 keys + pad

static __device__ __forceinline__ unsigned short f2bf(float f) {
    unsigned int u = __float_as_uint(f);
    u += 0x7fff + ((u >> 16) & 1);
    return (unsigned short)(u >> 16);
}
static __device__ __forceinline__ float bf2f(unsigned short h) {
    return __uint_as_float(((unsigned int)h) << 16);
}

// ---- fused prepass: K -> Kf [bh][key][d] fp16; V -> Vt [bh][d][key] fp16 ----
__global__ __launch_bounds__(256)
void conv_kv(const float* __restrict__ Kg, const float* __restrict__ Vg,
             _Float16* __restrict__ Kf, _Float16* __restrict__ Vt) {
    __shared__ float tile[64][65];
    const int kt = blockIdx.x;       // key tile 0..31
    const int bh = blockIdx.y;       // 0..63
    const int b  = bh >> 4, h = bh & 15;
    const int t  = threadIdx.x;
    const int row = t >> 2;          // 0..63
    const int seg = (t & 3) * 16;    // 0..48
    const size_t gsrc = (((size_t)(b * NL + kt * 64 + row) * NH + h) << 6) + seg;
    {   // K: straight vectorized convert
        float kv[16];
        #pragma unroll
        for (int i = 0; i < 16; i += 4) *(float4*)(kv + i) = *(const float4*)(Kg + gsrc + i);
        half8 o0, o1;
        #pragma unroll
        for (int j2 = 0; j2 < 8; ++j2) { o0[j2] = (_Float16)kv[j2]; o1[j2] = (_Float16)kv[8 + j2]; }
        _Float16* kd = Kf + (((size_t)(bh * NL + kt * 64 + row)) << 6) + seg;
        *(half8*)kd = o0;
        *(half8*)(kd + 8) = o1;
    }
    {   // V phase 1: fp32 tile into LDS
        #pragma unroll
        for (int i = 0; i < 16; i += 4) {
            float4 v = *(const float4*)(Vg + gsrc + i);
            tile[row][seg + i + 0] = v.x;
            tile[row][seg + i + 1] = v.y;
            tile[row][seg + i + 2] = v.z;
            tile[row][seg + i + 3] = v.w;
        }
    }
    __syncthreads();
    #pragma unroll
    for (int pass = 0; pass < 2; ++pass) {   // V phase 2: transpose out as fp16
        const int d  = pass * 32 + (t >> 3);
        const int kk = (t & 7) * 8;
        half8 o;
        #pragma unroll
        for (int j2 = 0; j2 < 8; ++j2) o[j2] = (_Float16)tile[kk + j2][d];
        *(half8*)(Vt + (((size_t)(bh * 64 + d)) << 11) + kt * 64 + kk) = o;
    }
}

// ------------------------------- main kernel --------------------------------
__global__ __launch_bounds__(512, 4)
void lsattn_main(const float* __restrict__ Qg,
                 const _Float16* __restrict__ Kf,
                 const _Float16* __restrict__ Vt,
                 float* __restrict__ Og) {
    __shared__ alignas(16) _Float16 Ks[64 * PADK];       // [key][d]
    __shared__ alignas(16) _Float16 Vs[64 * PADK];       // [d][key]
    __shared__ alignas(16) _Float16 Ps[8 * 16 * PADQ];   // per-wave P [q][key]

    const int id   = (int)blockIdx.x;        // 0..1023
    const int bh   = id & 63;
    const int pr   = id >> 6;                // 0..15
    const int tid  = threadIdx.x;
    const int lane = tid & 63;
    const int w    = tid >> 6;               // wave 0..7
    const int col  = lane & 15;
    const int quad = lane >> 4;

    const int sa   = (w < 4) ? pr : (31 - pr);   // this half's 64-q supertile
    const int qrow = sa * 64 + (w & 3) * 16 + col;

    // Q fragment fp32->fp16, B-operand layout: lane holds Q[qrow][c*32+quad*8+j]
    half8 qf[2];
    {
        const float* qp = Qg + (((size_t)((bh >> 4) * NL + qrow) * NH + (bh & 15)) << 6) + quad * 8;
        #pragma unroll
        for (int c = 0; c < 2; ++c) {
            float4 a = *(const float4*)(qp + c * 32);
            float4 b = *(const float4*)(qp + c * 32 + 4);
            qf[c][0] = (_Float16)a.x; qf[c][1] = (_Float16)a.y;
            qf[c][2] = (_Float16)a.z; qf[c][3] = (_Float16)a.w;
            qf[c][4] = (_Float16)b.x; qf[c][5] = (_Float16)b.y;
            qf[c][6] = (_Float16)b.z; qf[c][7] = (_Float16)b.w;
        }
    }

    floatx4 ofrag[4];
    #pragma unroll
    for (int i = 0; i < 4; ++i) ofrag[i] = floatx4{0.f, 0.f, 0.f, 0.f};
    float m_run = -1e30f, l_run = 0.f;

    // staging: thread covers 16B of one row; 512 threads cover 64 rows x 128B
    const int srow = tid >> 3;          // 0..63
    const int sseg = (tid & 7) * 8;     // 0..56
    const _Float16* kgb = Kf + (((size_t)(bh * NL)) << 6) + (srow << 6) + sseg;          // + t*4096
    const _Float16* vgb = Vt + (((size_t)bh) << 17) + ((size_t)srow << 11) + sseg;       // + t*64
    _Float16* pbuf = Ps + w * 16 * PADQ;

    const int TB = 31 - pr;             // block stages tiles 0..TB (union range)

    // prefetch tile 0 into registers
    half8 kpre = *(const half8*)(kgb);
    half8 vpre = *(const half8*)(vgb);

    for (int t = 0; t <= TB; ++t) {
        const int j0 = t * 64;
        __syncthreads();                 // tile t-1 consumers done
        *(half8*)(Ks + srow * PADK + sseg) = kpre;   // waits vmcnt internally
        *(half8*)(Vs + srow * PADK + sseg) = vpre;
        if (t < TB) {                    // issue next tile's loads BEFORE barrier:
            kpre = *(const half8*)(kgb + (t + 1) * 4096);   // latency overlaps
            vpre = *(const half8*)(vgb + (t + 1) * 64);     // barrier + compute
        }
        __syncthreads();                 // tile t visible

        if (t > sa) continue;            // short half idles (still stages above)

        // S^T = K * Q^T : stf[f][r] = score(key j0+f*16+quad*4+r, query qrow)
        floatx4 stf[4];
        #pragma unroll
        for (int f = 0; f < 4; ++f) {
            floatx4 acc = floatx4{0.f, 0.f, 0.f, 0.f};
            #pragma unroll
            for (int c = 0; c < 2; ++c) {
                half8 kfr = *(const half8*)(Ks + (f * 16 + col) * PADK + c * 32 + quad * 8);
                acc = __builtin_amdgcn_mfma_f32_16x16x32_f16(kfr, qf[c], acc, 0, 0, 0);
            }
            stf[f] = acc;
        }

        // causal mask only on this half's final tile
        if (t == sa) {
            #pragma unroll
            for (int f = 0; f < 4; ++f)
                #pragma unroll
                for (int r = 0; r < 4; ++r) {
                    const int key = j0 + f * 16 + quad * 4 + r;
                    if (key > qrow) stf[f][r] = -1e30f;
                }
        }

        // online softmax per query column (lanes {col, col+16, col+32, col+48})
        float mt = -1e30f;
        #pragma unroll
        for (int f = 0; f < 4; ++f)
            #pragma unroll
            for (int r = 0; r < 4; ++r) mt = fmaxf(mt, stf[f][r]);
        mt = fmaxf(mt, __shfl_xor(mt, 16));
        mt = fmaxf(mt, __shfl_xor(mt, 32));
        const float m_new = fmaxf(m_run, mt);
        const float alpha = __expf(m_run - m_new);
        float ls = 0.f;
        #pragma unroll
        for (int f = 0; f < 4; ++f)
            #pragma unroll
            for (int r = 0; r < 4; ++r) {
                const float p = __expf(stf[f][r] - m_new);
                stf[f][r] = p;
                ls += p;
            }
        ls += __shfl_xor(ls, 16);
        ls += __shfl_xor(ls, 32);
        l_run = l_run * alpha + ls;
        m_run = m_new;
        #pragma unroll
        for (int mc = 0; mc < 4; ++mc) ofrag[mc] *= alpha;

        // P^T via per-wave LDS round-trip (wave-private, no barrier)
        #pragma unroll
        for (int f = 0; f < 4; ++f) {
            half4 hp;
            hp[0] = (_Float16)stf[f][0]; hp[1] = (_Float16)stf[f][1];
            hp[2] = (_Float16)stf[f][2]; hp[3] = (_Float16)stf[f][3];
            *(half4*)(pbuf + col * PADQ + f * 16 + quad * 4) = hp;
        }
        half8 pf0 = *(const half8*)(pbuf + col * PADQ + quad * 8);
        half8 pf1 = *(const half8*)(pbuf + col * PADQ + 32 + quad * 8);

        // O^T += V^T * P^T
        #pragma unroll
        for (int mc = 0; mc < 4; ++mc) {
            half8 vf0 = *(const half8*)(Vs + (mc * 16 + col) * PADK + quad * 8);
            half8 vf1 = *(const half8*)(Vs + (mc * 16 + col) * PADK + 32 + quad * 8);
            ofrag[mc] = __builtin_amdgcn_mfma_f32_16x16x32_f16(vf0, pf0, ofrag[mc], 0, 0, 0);
            ofrag[mc] = __builtin_amdgcn_mfma_f32_16x16x32_f16(vf1, pf1, ofrag[mc], 0, 0, 0);
        }
    }

    // epilogue: divide by l, store fp32. Out [B,H,L,D]
    const float inv = 1.f / l_run;
    float* op = Og + ((size_t)bh * NL + qrow) * ND;
    #pragma unroll
    for (int mc = 0; mc < 4; ++mc) {
        float4 o;
        o.x = ofrag[mc][0] * inv;
        o.y = ofrag[mc][1] * inv;
        o.z = ofrag[mc][2] * inv;
        o.w = ofrag[mc][3] * inv;
        *(float4*)(op + mc * 16 + quad * 4) = o;
    }
}

// ===================== fallback (round-2 kernel, passed) =====================
__global__ __launch_bounds__(256)
void lsattn_fb(const float* __restrict__ Qg,
               const float* __restrict__ Kg,
               const float* __restrict__ Vg,
               float* __restrict__ Og) {
    __shared__ alignas(16) unsigned short Kh[64 * PADK];
    __shared__ alignas(16) unsigned short Kl[64 * PADK];
    __shared__ alignas(16) unsigned short Vh[64 * PADK];

    const int qt   = 31 - (int)blockIdx.x;
    const int bh   = blockIdx.y;
    const int tid  = threadIdx.x;
    const int lane = tid & 63;
    const int w    = tid >> 6;
    const int col  = lane & 15;
    const int quad = lane >> 4;
    const int qrow = qt * 64 + w * 16 + col;

    short8 qhi[2], qlo[2];
    {
        const float* qp = Qg + ((bh >> 4) * NL + qrow) * (NH * ND) + (bh & 15) * ND + quad * 8;
        #pragma unroll
        for (int c = 0; c < 2; ++c) {
            float qv[8];
            *(float4*)(qv + 0) = *(const float4*)(qp + c * 32);
            *(float4*)(qv + 4) = *(const float4*)(qp + c * 32 + 4);
            #pragma unroll
            for (int j = 0; j < 8; ++j) {
                unsigned short h = f2bf(qv[j]);
                qhi[c][j] = (short)h;
                qlo[c][j] = (short)f2bf(qv[j] - bf2f(h));
            }
        }
    }
    floatx4 ofrag[4];
    #pragma unroll
    for (int i = 0; i < 4; ++i) ofrag[i] = floatx4{0.f, 0.f, 0.f, 0.f};
    float m_run = -1e30f, l_run = 0.f;
    const int skey  = tid >> 2;
    const int sdb   = (tid & 3) * 16;
    const int gbase = (bh >> 4) * NL * NH * ND + (bh & 15) * ND;

    for (int t = 0; t <= qt; ++t) {
        const int j0 = t * 64;
        __syncthreads();
        {
            const int gro = gbase + (j0 + skey) * (NH * ND) + sdb;
            float kv[16], vv[16];
            #pragma unroll
            for (int i = 0; i < 16; i += 4) {
                *(float4*)(kv + i) = *(const float4*)(Kg + gro + i);
                *(float4*)(vv + i) = *(const float4*)(Vg + gro + i);
            }
            short8 h0, h1, l0, l1;
            #pragma unroll
            for (int j = 0; j < 8; ++j) {
                unsigned short h = f2bf(kv[j]);
                h0[j] = (short)h; l0[j] = (short)f2bf(kv[j] - bf2f(h));
                unsigned short g = f2bf(kv[8 + j]);
                h1[j] = (short)g; l1[j] = (short)f2bf(kv[8 + j] - bf2f(g));
            }
            *(short8*)(Kh + skey * PADK + sdb)     = h0;
            *(short8*)(Kh + skey * PADK + sdb + 8) = h1;
            *(short8*)(Kl + skey * PADK + sdb)     = l0;
            *(short8*)(Kl + skey * PADK + sdb + 8) = l1;
            #pragma unroll
            for (int i = 0; i < 16; ++i) Vh[(sdb + i) * PADK + skey] = f2bf(vv[i]);
        }
        __syncthreads();

        floatx4 stf[4];
        #pragma unroll
        for (int f = 0; f < 4; ++f) {
            floatx4 acc = floatx4{0.f, 0.f, 0.f, 0.f};
            #pragma unroll
            for (int c = 0; c < 2; ++c) {
                short8 kh = *(const short8*)(Kh + (f * 16 + col) * PADK + c * 32 + quad * 8);
                short8 kl = *(const short8*)(Kl + (f * 16 + col) * PADK + c * 32 + quad * 8);
                acc = __builtin_amdgcn_mfma_f32_16x16x32_bf16(kh, qhi[c], acc, 0, 0, 0);
                acc = __builtin_amdgcn_mfma_f32_16x16x32_bf16(kl, qhi[c], acc, 0, 0, 0);
                acc = __builtin_amdgcn_mfma_f32_16x16x32_bf16(kh, qlo[c], acc, 0, 0, 0);
            }
            stf[f] = acc;
        }
        if (t == qt) {
            #pragma unroll
            for (int f = 0; f < 4; ++f)
                #pragma unroll
                for (int r = 0; r < 4; ++r) {
                    const int key = j0 + f * 16 + quad * 4 + r;
                    if (key > qrow) stf[f][r] = -1e30f;
                }
        }
        float mt = -1e30f;
        #pragma unroll
        for (int f = 0; f < 4; ++f)
            #pragma unroll
            for (int r = 0; r < 4; ++r) mt = fmaxf(mt, stf[f][r]);
        mt = fmaxf(mt, __shfl_xor(mt, 16));
        mt = fmaxf(mt, __shfl_xor(mt, 32));
        const float m_new = fmaxf(m_run, mt);
        const float alpha = __expf(m_run - m_new);
        float ls = 0.f;
        #pragma unroll
        for (int f = 0; f < 4; ++f)
            #pragma unroll
            for (int r = 0; r < 4; ++r) {
                const float p = __expf(stf[f][r] - m_new);
                stf[f][r] = p; ls += p;
            }
        ls += __shfl_xor(ls, 16);
        ls += __shfl_xor(ls, 32);
        l_run = l_run * alpha + ls;
        m_run = m_new;
        #pragma unroll
        for (int mc = 0; mc < 4; ++mc) ofrag[mc] *= alpha;

        short8 pfrag[2];
        #pragma unroll
        for (int kc = 0; kc < 2; ++kc) {
            #pragma unroll
            for (int jj = 0; jj < 8; ++jj) {
                const int r  = jj & 3;
                const int sq = (quad & 1) * 2 + (jj >> 2);
                const int sl = col + (sq << 4);
                const float va = __shfl(stf[kc * 2 + 0][r], sl);
                const float vb = __shfl(stf[kc * 2 + 1][r], sl);
                pfrag[kc][jj] = (short)f2bf((quad & 2) ? vb : va);
            }
        }
        #pragma unroll
        for (int mc = 0; mc < 4; ++mc) {
            #pragma unroll
            for (int kc = 0; kc < 2; ++kc) {
                short8 vf = *(const short8*)(Vh + (mc * 16 + col) * PADK + kc * 32 + quad * 8);
                ofrag[mc] = __builtin_amdgcn_mfma_f32_16x16x32_bf16(vf, pfrag[kc], ofrag[mc], 0, 0, 0);
            }
        }
    }
    const float inv = 1.f / l_run;
    float* op = Og + ((size_t)bh * NL + qrow) * ND;
    #pragma unroll
    for (int mc = 0; mc < 4; ++mc) {
        float4 o;
        o.x = ofrag[mc][0] * inv; o.y = ofrag[mc][1] * inv;
        o.z = ofrag[mc][2] * inv; o.w = ofrag[mc][3] * inv;
        *(float4*)(op + mc * 16 + quad * 4) = o;
    }
}

extern "C" void kernel_launch(void* const* d_in, const int* in_sizes, int n_in,
                              void* d_out, int out_size, void* d_ws, size_t ws_size,
                              hipStream_t stream) {
    const float* Q = (const float*)d_in[0];
    const float* K = (const float*)d_in[1];
    const float* V = (const float*)d_in[2];
    float* O = (float*)d_out;

    const size_t elems = (size_t)NB * NL * NH * ND;          // 8,388,608
    if (ws_size >= 2 * elems * sizeof(_Float16)) {           // 32 MiB needed
        _Float16* Kf = (_Float16*)d_ws;
        _Float16* Vt = Kf + elems;
        conv_kv<<<dim3(32, 64), dim3(256), 0, stream>>>(K, V, Kf, Vt);
        lsattn_main<<<dim3(1024), dim3(512), 0, stream>>>(Q, Kf, Vt, O);
    } else {
        lsattn_fb<<<dim3(32, 64), dim3(256), 0, stream>>>(Q, K, V, O);
    }
}